// Round 8
// baseline (6678.860 us; speedup 1.0000x reference)
//
#include <hip/hip_runtime.h>
#include <hip/hip_bf16.h>

// SimpleBiGRU on MI355X — R7: XCC_ID roll-call + XCD-local L2 sync.
// Both "directions" are forward-in-time GRU scans (batch-flip is identity).
// 8 units = (dir) x (batch-group of 16 rows); unit u is served by the 32 WGs
// that physically land on XCD u (claimed at runtime via HW_REG_XCC_ID), each
// owning 16 hidden columns x 3 gates.
//
// Claim phase: slot = atomicAdd(claim[xcc]); slot<32 => own (xcc, slot),
// mark loc[]; grid barrier; surplus WGs adopt the r-th unclaimed slice;
// unit llcMode = any slice not locally owned. Pure mode: publish = plain
// store into the shared XCD L2 (+ LLC mirror for hang-safety), poll = sc0
// loads (L1-bypass, L2-hit) with an LLC check every 8th failed iteration.
// llcMode: exactly the R4b LLC protocol.
//
// h broadcast: u32 = (bf16 << 16) | tag, tag = step+1; consumer accepts when
// all 32 of its fragment chunks carry tag t (tags at words 0/3 cover both 8B
// store granules). Double buffer => no WG runs >1 step ahead.
//
// MFMA (swapped operands, layout-safe k-slot mapping k = ks*32 + lg*8 + j):
//   acc = MFMA(W_frag, act_frag, acc); D: row = 4*lg+reg = out-col offset,
//   col = l15 = batch row. Lane owns 4 adjacent h-cols of one batch row.

#define TT 512
#define FF 256
#define HH 512
#define G3 1536
#define NWG 256
#define NTHR 64

// control block indices (ints)
#define C_CLAIM   0    // [8]
#define C_SURPLUS 8
#define C_DONE1   9
#define C_DONE2   10
#define C_LOC     16   // [256]

typedef __attribute__((ext_vector_type(8))) short short8;   // 8 x bf16
typedef __attribute__((ext_vector_type(4))) float f32x4;
typedef unsigned int u32;
typedef unsigned long long u64;

union U4 { uint4 v; u32 u[4]; u64 q[2]; };

__device__ __forceinline__ unsigned short f2bf(float f) {
  union { float f; unsigned u; } x; x.f = f;
  return (unsigned short)((x.u + 0x7fffu + ((x.u >> 16) & 1u)) >> 16);  // RNE
}

__device__ __forceinline__ unsigned pk2(float a, float b) {
  union { __hip_bfloat162 h; unsigned u; } x;
  x.h = __float22bfloat162_rn(make_float2(a, b));
  return x.u;  // low 16 = a, high 16 = b
}

__device__ __forceinline__ float sigm(float x) {
  return __builtin_amdgcn_rcpf(1.f + __expf(-x));
}

#define MFMA(a, b, c) __builtin_amdgcn_mfma_f32_16x16x32_bf16((a), (b), (c), 0, 0, 0)

__global__ __launch_bounds__(NTHR, 1) void gru_fused(
    const float* __restrict__ data,
    const float* __restrict__ Wi_f, const float* __restrict__ bi_f,
    const float* __restrict__ Wh_f, const float* __restrict__ bhn_f,
    const float* __restrict__ Wi_b, const float* __restrict__ bi_b,
    const float* __restrict__ Wh_b, const float* __restrict__ bhn_b,
    float* __restrict__ out,
    u32* __restrict__ hbufL,   // L2-local tagged region [unit][buf][16][512]
    u32* __restrict__ hbufG,   // LLC tagged region      [unit][buf][16][512]
    int* __restrict__ ctrl)
{
  const int lane = threadIdx.x; // 0..63
  const int l15  = lane & 15;
  const int lg   = lane >> 4;

  // ---- claim phase: which XCD am I on? ----
  unsigned xcc;
  asm("s_getreg_b32 %0, hwreg(HW_REG_XCC_ID)" : "=s"(xcc));
  xcc &= 7;

  int slot = 0, rsur = 0;
  if (lane == 0) {
    slot = __hip_atomic_fetch_add(&ctrl[C_CLAIM + xcc], 1,
                                  __ATOMIC_RELAXED, __HIP_MEMORY_SCOPE_AGENT);
    if (slot >= 32)
      rsur = __hip_atomic_fetch_add(&ctrl[C_SURPLUS], 1,
                                    __ATOMIC_RELAXED, __HIP_MEMORY_SCOPE_AGENT);
  }
  slot = __shfl(slot, 0);
  rsur = __shfl(rsur, 0);

  int unit = (int)xcc, s = slot;
  if (slot < 32) {
    if (lane == 0)
      __hip_atomic_store(&ctrl[C_LOC + unit * 32 + s], 1,
                         __ATOMIC_RELEASE, __HIP_MEMORY_SCOPE_AGENT);
  }
  if (lane == 0)
    __hip_atomic_fetch_add(&ctrl[C_DONE1], 1, __ATOMIC_ACQ_REL, __HIP_MEMORY_SCOPE_AGENT);
  while (__hip_atomic_load(&ctrl[C_DONE1], __ATOMIC_ACQUIRE, __HIP_MEMORY_SCOPE_AGENT) < NWG) {}

  if (slot >= 32) {  // adopt the rsur-th unclaimed (unit, slice)
    int cnt = 0;
    for (int i = 0; i < 256; ++i) {
      int v = __hip_atomic_load(&ctrl[C_LOC + i], __ATOMIC_RELAXED, __HIP_MEMORY_SCOPE_AGENT);
      if (!v) { if (cnt == rsur) { unit = i >> 5; s = i & 31; break; } ++cnt; }
    }
  }
  // unit mode: pure-L2 iff all 32 slices locally owned
  int locv = (lane < 32)
      ? __hip_atomic_load(&ctrl[C_LOC + unit * 32 + lane], __ATOMIC_RELAXED, __HIP_MEMORY_SCOPE_AGENT)
      : 1;
  const bool llcMode = __any(locv == 0);

  // re-seed own tag-0 lines through this XCD's L2 (kills cross-replay stale
  // dirty lines), then barrier 2 so nobody polls before seeding completes.
  if (!llcMode) {
#pragma unroll
    for (int b = 0; b < 2; ++b) {
      u64* p = (u64*)(hbufL + ((size_t)(unit * 2 + b) << 13) + l15 * 512 + s * 16 + lg * 4);
      __hip_atomic_store(&p[0], 0ull, __ATOMIC_RELAXED, __HIP_MEMORY_SCOPE_WORKGROUP);
      __hip_atomic_store(&p[1], 0ull, __ATOMIC_RELAXED, __HIP_MEMORY_SCOPE_WORKGROUP);
    }
  }
  asm volatile("s_waitcnt vmcnt(0)" ::: "memory");
  if (lane == 0)
    __hip_atomic_fetch_add(&ctrl[C_DONE2], 1, __ATOMIC_ACQ_REL, __HIP_MEMORY_SCOPE_AGENT);
  while (__hip_atomic_load(&ctrl[C_DONE2], __ATOMIC_ACQUIRE, __HIP_MEMORY_SCOPE_AGENT) < NWG) {}

  // ---- per-WG role ----
  const int dir = unit >> 2;
  const int bg  = unit & 3;

  const float* Wi  = dir ? Wi_b  : Wi_f;
  const float* Wh  = dir ? Wh_b  : Wh_f;
  const float* bi  = dir ? bi_b  : bi_f;
  const float* bhn = dir ? bhn_b : bhn_f;

  const int colT = s * 16 + l15;        // weight-fragment column (A m-index)
  const int colBase = s * 16 + lg * 4;  // this lane's 4 output columns

  // ---- one-time: weight A-fragments into registers (k = ks*32+lg*8+j) ----
  short8 whf[3][16];
#pragma unroll
  for (int g = 0; g < 3; ++g)
#pragma unroll
    for (int ks = 0; ks < 16; ++ks) {
      short8 v;
#pragma unroll
      for (int j = 0; j < 8; ++j)
        v[j] = (short)f2bf(Wh[(size_t)(ks * 32 + lg * 8 + j) * G3 + g * HH + colT]);
      whf[g][ks] = v;
    }
  short8 wif[3][8];
#pragma unroll
  for (int g = 0; g < 3; ++g)
#pragma unroll
    for (int ks = 0; ks < 8; ++ks) {
      short8 v;
#pragma unroll
      for (int j = 0; j < 8; ++j)
        v[j] = (short)f2bf(Wi[(size_t)(ks * 32 + lg * 8 + j) * G3 + g * HH + colT]);
      wif[g][ks] = v;
    }
  float biR[4], biZ[4], biN[4], bhc[4];
#pragma unroll
  for (int j = 0; j < 4; ++j) {
    biR[j] = bi[colBase + j];
    biZ[j] = bi[HH + colBase + j];
    biN[j] = bi[2 * HH + colBase + j];
    bhc[j] = bhn[colBase + j];
  }

  const float* xbase = data + (size_t)(bg * 16 + l15) * TT * FF;
  float hp[4] = {0.f, 0.f, 0.f, 0.f};  // fp32 carry: batch l15, cols colBase+j

  for (int t = 0; t < TT; ++t) {
    // ---- xg phase (h-independent; issues before the poll) ----
    f32x4 accR = {0.f, 0.f, 0.f, 0.f};
    f32x4 accZ = {0.f, 0.f, 0.f, 0.f};
    f32x4 xN   = {0.f, 0.f, 0.f, 0.f};
    {
      const float* xr = xbase + (size_t)t * FF;
#pragma unroll
      for (int ks = 0; ks < 8; ++ks) {
        float4 x0 = *(const float4*)(xr + ks * 32 + lg * 8);
        float4 x1 = *(const float4*)(xr + ks * 32 + lg * 8 + 4);
        union { short8 s; unsigned u[4]; } a;
        a.u[0] = pk2(x0.x, x0.y); a.u[1] = pk2(x0.z, x0.w);
        a.u[2] = pk2(x1.x, x1.y); a.u[3] = pk2(x1.z, x1.w);
        accR = MFMA(wif[0][ks], a.s, accR);
        accZ = MFMA(wif[1][ks], a.s, accZ);
        xN   = MFMA(wif[2][ks], a.s, xN);
      }
    }

    // ---- tagged poll ----
    const u32 tag = (u32)t;
    const size_t boff = (size_t)(unit * 2 + (t & 1)) << 13;  // 16*512 u32
    const u32* hbL = hbufL + boff;
    const u32* hbG = hbufG + boff;
    U4 q[32];
    int it = 0;
    while (true) {
      const bool g = llcMode | ((it & 7) == 7);   // wave-uniform
      if (g) {
#pragma unroll
        for (int ks = 0; ks < 16; ++ks) {
          const u32* p = hbG + l15 * 512 + ks * 32 + lg * 8;
          asm volatile("global_load_dwordx4 %0, %1, off sc0 sc1"
                       : "=v"(q[2 * ks].v) : "v"(p));
          asm volatile("global_load_dwordx4 %0, %1, off sc0 sc1"
                       : "=v"(q[2 * ks + 1].v) : "v"(p + 4));
        }
      } else {
#pragma unroll
        for (int ks = 0; ks < 16; ++ks) {
          const u32* p = hbL + l15 * 512 + ks * 32 + lg * 8;
          asm volatile("global_load_dwordx4 %0, %1, off sc0"
                       : "=v"(q[2 * ks].v) : "v"(p));
          asm volatile("global_load_dwordx4 %0, %1, off sc0"
                       : "=v"(q[2 * ks + 1].v) : "v"(p + 4));
        }
      }
      asm volatile("s_waitcnt vmcnt(0)" ::: "memory");
      u32 bad = 0;
#pragma unroll
      for (int c = 0; c < 32; ++c) {
        bad |= (q[c].u[0] ^ tag) & 0xffffu;   // tag of 8B granule {w0,w1}
        bad |= (q[c].u[3] ^ tag) & 0xffffu;   // tag of 8B granule {w2,w3}
      }
      if (__all(bad == 0)) break;
      ++it;
    }

    // ---- pack B-fragments (strip tags) + hg MFMAs ----
    f32x4 hN = {0.f, 0.f, 0.f, 0.f};
#pragma unroll
    for (int ks = 0; ks < 16; ++ks) {
      union { short8 s; unsigned u[4]; } a;
#pragma unroll
      for (int i = 0; i < 2; ++i) {
        const U4& c = q[2 * ks + i];
        a.u[2 * i]     = __builtin_amdgcn_perm(c.u[1], c.u[0], 0x07060302u);
        a.u[2 * i + 1] = __builtin_amdgcn_perm(c.u[3], c.u[2], 0x07060302u);
      }
      accR = MFMA(whf[0][ks], a.s, accR);
      accZ = MFMA(whf[1][ks], a.s, accZ);
      hN   = MFMA(whf[2][ks], a.s, hN);
    }

    // ---- gates: lane holds (batch=l15, cols=colBase..+3) ----
    float hv[4];
#pragma unroll
    for (int j = 0; j < 4; ++j) {
      float r = sigm(accR[j] + biR[j]);
      float z = sigm(accZ[j] + biZ[j]);
      float e = __expf(2.f * (xN[j] + biN[j] + r * (hN[j] + bhc[j])));
      float n = 1.f - 2.f * __builtin_amdgcn_rcpf(e + 1.f);  // tanh
      hv[j] = (1.f - z) * n + z * hp[j];
      hp[j] = hv[j];
    }

    // ---- publish ----
    {
      U4 w;
      const u32 wtag = (u32)(t + 1);
#pragma unroll
      for (int j = 0; j < 4; ++j)
        w.u[j] = ((u32)f2bf(hv[j]) << 16) | wtag;
      const size_t ooff = ((size_t)(unit * 2 + ((t + 1) & 1)) << 13)
                        + l15 * 512 + s * 16 + lg * 4;
      if (!llcMode) {   // fast path: into this XCD's L2 (+ LLC mirror)
        u64* pL = (u64*)(hbufL + ooff);
        __hip_atomic_store(&pL[0], w.q[0], __ATOMIC_RELAXED, __HIP_MEMORY_SCOPE_WORKGROUP);
        __hip_atomic_store(&pL[1], w.q[1], __ATOMIC_RELAXED, __HIP_MEMORY_SCOPE_WORKGROUP);
      }
      u64* pG = (u64*)(hbufG + ooff);
      __hip_atomic_store(&pG[0], w.q[0], __ATOMIC_RELAXED, __HIP_MEMORY_SCOPE_AGENT);
      __hip_atomic_store(&pG[1], w.q[1], __ATOMIC_RELAXED, __HIP_MEMORY_SCOPE_AGENT);
    }

    // ---- out store (off critical path): one float4 per lane ----
    *(float4*)(out + ((size_t)(bg * 16 + l15) * TT + t) * 1024 + (size_t)dir * HH + colBase)
        = make_float4(hv[0], hv[1], hv[2], hv[3]);
  }
}

extern "C" void kernel_launch(void* const* d_in, const int* in_sizes, int n_in,
                              void* d_out, int out_size, void* d_ws, size_t ws_size,
                              hipStream_t stream) {
  const float* data  = (const float*)d_in[0];
  const float* Wi_f  = (const float*)d_in[1];
  const float* bi_f  = (const float*)d_in[2];
  const float* Wh_f  = (const float*)d_in[3];
  const float* bhn_f = (const float*)d_in[4];
  const float* Wi_b  = (const float*)d_in[5];
  const float* bi_b  = (const float*)d_in[6];
  const float* Wh_b  = (const float*)d_in[7];
  const float* bhn_b = (const float*)d_in[8];
  float* out = (float*)d_out;

  // ws: [0,512K) hbufL; [512K,1M) hbufG; [1M,+4K) ctrl. memset all (tag-0
  // zero state is valid initial data => uniform t=0 path).
  u32* hbufL = (u32*)d_ws;
  u32* hbufG = (u32*)((char*)d_ws + 524288);
  int* ctrl  = (int*)((char*)d_ws + 1048576);
  (void)hipMemsetAsync(d_ws, 0, 1048576 + 4096, stream);

  gru_fused<<<NWG, NTHR, 0, stream>>>(data, Wi_f, bi_f, Wh_f, bhn_f,
                                      Wi_b, bi_b, Wh_b, bhn_b, out,
                                      hbufL, hbufG, ctrl);
}

// Round 10
// 5362.522 us; speedup vs baseline: 1.2455x; 1.2455x over previous
//
#include <hip/hip_runtime.h>
#include <hip/hip_bf16.h>

// SimpleBiGRU on MI355X — R9: flags + h broadcast THROUGH d_out (fp32, cached).
// Both "directions" are forward-in-time GRU scans (batch-flip is identity).
// 8 units = (dir) x (batch-group of 16 rows); 32 WGs (1 wave) per unit, each
// owning 16 h-columns x 3 gates, weights in VGPRs.
//
// Key insight: h_dir(t)[b][col] IS out[b][t][dir*512+col]. The producer's
// output store doubles as the h broadcast. Every (t,b,col) address is
// written exactly once per replay with deterministic (replay-invariant)
// bytes, so cached reads of d_out are correct even if a cache serves a
// stale line from a previous replay — the bytes are identical. First-call
// freshness is ordered by the flag protocol: agent-scope data stores ->
// vmcnt(0) -> agent-scope flag store; consumer polls flags (uncached,
// 4B/lane) and only then reads the data (cache miss -> LLC has the
// agent-written values).
//
// Consumer poll = 256B/iter (vs 32KB/iter in R4b) => small detection
// quantization => smaller max-of-32-producers straggler penalty.
//
// MFMA (swapped operands, layout-safe k-slot mapping k = ks*32 + lg*8 + j):
//   acc = MFMA(W_frag, act_frag, acc); D: row = 4*lg+reg = out-col offset,
//   col = l15 = batch row. Lane owns 4 adjacent h-cols of one batch row.

#define TT 512
#define FF 256
#define HH 512
#define G3 1536
#define NWG 256
#define NTHR 64

typedef __attribute__((ext_vector_type(8))) short short8;   // 8 x bf16
typedef __attribute__((ext_vector_type(4))) float f32x4;
typedef unsigned int u32;
typedef unsigned long long u64;

__device__ __forceinline__ unsigned short f2bf(float f) {
  union { float f; unsigned u; } x; x.f = f;
  return (unsigned short)((x.u + 0x7fffu + ((x.u >> 16) & 1u)) >> 16);  // RNE
}

__device__ __forceinline__ unsigned pk2(float a, float b) {
  union { __hip_bfloat162 h; unsigned u; } x;
  x.h = __float22bfloat162_rn(make_float2(a, b));
  return x.u;  // low 16 = a, high 16 = b
}

__device__ __forceinline__ float sigm(float x) {
  return __builtin_amdgcn_rcpf(1.f + __expf(-x));
}

#define MFMA(a, b, c) __builtin_amdgcn_mfma_f32_16x16x32_bf16((a), (b), (c), 0, 0, 0)

__global__ __launch_bounds__(NTHR, 1) void gru_fused(
    const float* __restrict__ data,
    const float* __restrict__ Wi_f, const float* __restrict__ bi_f,
    const float* __restrict__ Wh_f, const float* __restrict__ bhn_f,
    const float* __restrict__ Wi_b, const float* __restrict__ bi_b,
    const float* __restrict__ Wh_b, const float* __restrict__ bhn_b,
    float* __restrict__ out,
    u32* __restrict__ flags)   // [unit][32] = published step+1
{
  const int wg   = blockIdx.x;
  const int unit = wg & 7;
  const int s    = wg >> 3;     // column slice 0..31
  const int dir  = unit >> 2;
  const int bg   = unit & 3;
  const int lane = threadIdx.x; // 0..63
  const int l15  = lane & 15;
  const int lg   = lane >> 4;

  const float* Wi  = dir ? Wi_b  : Wi_f;
  const float* Wh  = dir ? Wh_b  : Wh_f;
  const float* bi  = dir ? bi_b  : bi_f;
  const float* bhn = dir ? bhn_b : bhn_f;

  const int colT = s * 16 + l15;        // weight-fragment column (A m-index)
  const int colBase = s * 16 + lg * 4;  // this lane's 4 output columns

  // ---- one-time: weight A-fragments into registers (k = ks*32+lg*8+j) ----
  short8 whf[3][16];
#pragma unroll
  for (int g = 0; g < 3; ++g)
#pragma unroll
    for (int ks = 0; ks < 16; ++ks) {
      short8 v;
#pragma unroll
      for (int j = 0; j < 8; ++j)
        v[j] = (short)f2bf(Wh[(size_t)(ks * 32 + lg * 8 + j) * G3 + g * HH + colT]);
      whf[g][ks] = v;
    }
  short8 wif[3][8];
#pragma unroll
  for (int g = 0; g < 3; ++g)
#pragma unroll
    for (int ks = 0; ks < 8; ++ks) {
      short8 v;
#pragma unroll
      for (int j = 0; j < 8; ++j)
        v[j] = (short)f2bf(Wi[(size_t)(ks * 32 + lg * 8 + j) * G3 + g * HH + colT]);
      wif[g][ks] = v;
    }
  float biR[4], biZ[4], biN[4], bhc[4];
#pragma unroll
  for (int j = 0; j < 4; ++j) {
    biR[j] = bi[colBase + j];
    biZ[j] = bi[HH + colBase + j];
    biN[j] = bi[2 * HH + colBase + j];
    bhc[j] = bhn[colBase + j];
  }

  const float* xbase = data + (size_t)(bg * 16 + l15) * TT * FF;
  // h(t-1) read base: row (bg*16+l15) of out, dir half
  const float* hbase = out + (size_t)(bg * 16 + l15) * TT * 1024 + (size_t)dir * HH;
  u32* myflags = flags + unit * 32;
  const u32* fp = myflags + (lane & 31);

  float hp[4] = {0.f, 0.f, 0.f, 0.f};  // fp32 carry: batch l15, cols colBase+j

  for (int t = 0; t < TT; ++t) {
    // ---- xg phase (h-independent; issues before the poll) ----
    f32x4 accR = {0.f, 0.f, 0.f, 0.f};
    f32x4 accZ = {0.f, 0.f, 0.f, 0.f};
    f32x4 xN   = {0.f, 0.f, 0.f, 0.f};
    {
      const float* xr = xbase + (size_t)t * FF;
#pragma unroll
      for (int ks = 0; ks < 8; ++ks) {
        float4 x0 = *(const float4*)(xr + ks * 32 + lg * 8);
        float4 x1 = *(const float4*)(xr + ks * 32 + lg * 8 + 4);
        union { short8 s; unsigned u[4]; } a;
        a.u[0] = pk2(x0.x, x0.y); a.u[1] = pk2(x0.z, x0.w);
        a.u[2] = pk2(x1.x, x1.y); a.u[3] = pk2(x1.z, x1.w);
        accR = MFMA(wif[0][ks], a.s, accR);
        accZ = MFMA(wif[1][ks], a.s, accZ);
        xN   = MFMA(wif[2][ks], a.s, xN);
      }
    }

    f32x4 hN = {0.f, 0.f, 0.f, 0.f};
    if (t > 0) {
      // ---- tiny flag poll: 4B/lane uncached, all 32 producer flags >= t ----
      u32 fl;
      while (true) {
        asm volatile("global_load_dword %0, %1, off sc0 sc1"
                     : "=v"(fl) : "v"(fp));
        asm volatile("s_waitcnt vmcnt(0)" ::: "memory");
        if (__all(fl >= (u32)t)) break;
      }
      asm volatile("" ::: "memory");  // keep h loads below the poll

      // ---- bulk h(t-1) read from d_out (cached fp32) + hg MFMAs ----
      const float* hr = hbase + (size_t)(t - 1) * 1024;
#pragma unroll
      for (int ks = 0; ks < 16; ++ks) {
        float4 h0 = *(const float4*)(hr + ks * 32 + lg * 8);
        float4 h1 = *(const float4*)(hr + ks * 32 + lg * 8 + 4);
        union { short8 s; unsigned u[4]; } a;
        a.u[0] = pk2(h0.x, h0.y); a.u[1] = pk2(h0.z, h0.w);
        a.u[2] = pk2(h1.x, h1.y); a.u[3] = pk2(h1.z, h1.w);
        accR = MFMA(whf[0][ks], a.s, accR);
        accZ = MFMA(whf[1][ks], a.s, accZ);
        hN   = MFMA(whf[2][ks], a.s, hN);
      }
    }
    // t == 0: h(-1) = 0 -> hg contribution is zero; skip poll and reads.

    // ---- gates: lane holds (batch=l15, cols=colBase..+3) ----
    float hv[4];
#pragma unroll
    for (int j = 0; j < 4; ++j) {
      float r = sigm(accR[j] + biR[j]);
      float z = sigm(accZ[j] + biZ[j]);
      float e = __expf(2.f * (xN[j] + biN[j] + r * (hN[j] + bhc[j])));
      float n = 1.f - 2.f * __builtin_amdgcn_rcpf(e + 1.f);  // tanh
      hv[j] = (1.f - z) * n + z * hp[j];
      hp[j] = hv[j];
    }

    // ---- publish: h(t) IS the output. Agent-scope stores -> drain -> flag --
    {
      union { float f[2]; u64 q; } p0, p1;
      p0.f[0] = hv[0]; p0.f[1] = hv[1];
      p1.f[0] = hv[2]; p1.f[1] = hv[3];
      u64* po = (u64*)(out + ((size_t)(bg * 16 + l15) * TT + t) * 1024
                       + (size_t)dir * HH + colBase);
      __hip_atomic_store(&po[0], p0.q, __ATOMIC_RELAXED, __HIP_MEMORY_SCOPE_AGENT);
      __hip_atomic_store(&po[1], p1.q, __ATOMIC_RELAXED, __HIP_MEMORY_SCOPE_AGENT);
      asm volatile("s_waitcnt vmcnt(0)" ::: "memory");  // data before flag
      if (lane == 0)
        __hip_atomic_store(&myflags[s], (u32)(t + 1),
                           __ATOMIC_RELAXED, __HIP_MEMORY_SCOPE_AGENT);
    }
  }
}

extern "C" void kernel_launch(void* const* d_in, const int* in_sizes, int n_in,
                              void* d_out, int out_size, void* d_ws, size_t ws_size,
                              hipStream_t stream) {
  const float* data  = (const float*)d_in[0];
  const float* Wi_f  = (const float*)d_in[1];
  const float* bi_f  = (const float*)d_in[2];
  const float* Wh_f  = (const float*)d_in[3];
  const float* bhn_f = (const float*)d_in[4];
  const float* Wi_b  = (const float*)d_in[5];
  const float* bi_b  = (const float*)d_in[6];
  const float* Wh_b  = (const float*)d_in[7];
  const float* bhn_b = (const float*)d_in[8];
  float* out = (float*)d_out;

  // ws: [0, 1KB) flags (8 units x 32 producers). Zero each launch: flag
  // value t+1 > 0, so 0 == "nothing published yet".
  u32* flags = (u32*)d_ws;
  (void)hipMemsetAsync(d_ws, 0, 1024, stream);

  gru_fused<<<NWG, NTHR, 0, stream>>>(data, Wi_f, bi_f, Wh_f, bhn_f,
                                      Wi_b, bi_b, Wh_b, bhn_b, out, flags);
}

// Round 11
// 3764.480 us; speedup vs baseline: 1.7742x; 1.4245x over previous
//
#include <hip/hip_runtime.h>
#include <hip/hip_bf16.h>

// SimpleBiGRU on MI355X — R10: R4b + remote-execute atomic publish.
// Both "directions" are forward-in-time GRU scans (batch-flip is identity).
// 8 units = (dir) x (batch-group of 16 rows); 32 WGs (1 wave each) per unit,
// each owning 16 hidden columns x 3 gates.
//
// h broadcast format: u32 = (bf16 value << 16) | tag, tag = step+1.
// Consumer at step t polls its own 32 MFMA-fragment chunks (16B each) until
// ALL tags == t (tags at words 0/3 cover both 8B granules); values are then
// already in registers. Double buffer + every-WG-is-both-producer-and-
// consumer => nobody runs >1 step ahead => no overwrite hazard.
//
// R10 change (the experiment): publish uses __hip_atomic_exchange
// (global_atomic_swap_x2) instead of plain agent stores. Atomics execute AT
// the LLC — data is visible the moment the request packet arrives (one
// fabric transit), bypassing the plain-store writeback path that the
// R3/R4b/R7/R9 step-time table implicates as the ~5-6 us/step cost.
//
// MFMA convention (swapped, layout-safe k-slot mapping k = ks*32 + lg*8 + j):
//   acc = MFMA(W_frag, act_frag, acc); D: row = 4*lg+reg = out-col offset,
//   col = l15 = batch row. Lane owns 4 adjacent h-cols of one batch row.

#define TT 512
#define FF 256
#define HH 512
#define G3 1536
#define NWG 256
#define NTHR 64

typedef __attribute__((ext_vector_type(8))) short short8;   // 8 x bf16
typedef __attribute__((ext_vector_type(4))) float f32x4;
typedef unsigned int u32;
typedef unsigned long long u64;

union U4 { uint4 v; u32 u[4]; u64 q[2]; };

__device__ __forceinline__ unsigned short f2bf(float f) {
  union { float f; unsigned u; } x; x.f = f;
  return (unsigned short)((x.u + 0x7fffu + ((x.u >> 16) & 1u)) >> 16);  // RNE
}

__device__ __forceinline__ unsigned pk2(float a, float b) {
  union { __hip_bfloat162 h; unsigned u; } x;
  x.h = __float22bfloat162_rn(make_float2(a, b));
  return x.u;  // low 16 = a, high 16 = b
}

__device__ __forceinline__ float sigm(float x) {
  return __builtin_amdgcn_rcpf(1.f + __expf(-x));
}

#define MFMA(a, b, c) __builtin_amdgcn_mfma_f32_16x16x32_bf16((a), (b), (c), 0, 0, 0)

__global__ __launch_bounds__(NTHR, 1) void gru_fused(
    const float* __restrict__ data,
    const float* __restrict__ Wi_f, const float* __restrict__ bi_f,
    const float* __restrict__ Wh_f, const float* __restrict__ bhn_f,
    const float* __restrict__ Wi_b, const float* __restrict__ bi_b,
    const float* __restrict__ Wh_b, const float* __restrict__ bhn_b,
    float* __restrict__ out,
    u32* __restrict__ hbuf)   // [unit][buf][row16][col512] tagged u32
{
  const int wg   = blockIdx.x;
  const int unit = wg & 7;
  const int s    = wg >> 3;     // column slice 0..31
  const int dir  = unit >> 2;
  const int bg   = unit & 3;
  const int lane = threadIdx.x; // 0..63
  const int l15  = lane & 15;
  const int lg   = lane >> 4;

  const float* Wi  = dir ? Wi_b  : Wi_f;
  const float* Wh  = dir ? Wh_b  : Wh_f;
  const float* bi  = dir ? bi_b  : bi_f;
  const float* bhn = dir ? bhn_b : bhn_f;

  const int colT = s * 16 + l15;        // weight-fragment column (A m-index)
  const int colBase = s * 16 + lg * 4;  // this lane's 4 output columns

  // ---- one-time: weight A-fragments into registers (k = ks*32+lg*8+j) ----
  short8 whf[3][16];
#pragma unroll
  for (int g = 0; g < 3; ++g)
#pragma unroll
    for (int ks = 0; ks < 16; ++ks) {
      short8 v;
#pragma unroll
      for (int j = 0; j < 8; ++j)
        v[j] = (short)f2bf(Wh[(size_t)(ks * 32 + lg * 8 + j) * G3 + g * HH + colT]);
      whf[g][ks] = v;
    }
  short8 wif[3][8];
#pragma unroll
  for (int g = 0; g < 3; ++g)
#pragma unroll
    for (int ks = 0; ks < 8; ++ks) {
      short8 v;
#pragma unroll
      for (int j = 0; j < 8; ++j)
        v[j] = (short)f2bf(Wi[(size_t)(ks * 32 + lg * 8 + j) * G3 + g * HH + colT]);
      wif[g][ks] = v;
    }
  float biR[4], biZ[4], biN[4], bhc[4];
#pragma unroll
  for (int j = 0; j < 4; ++j) {
    biR[j] = bi[colBase + j];
    biZ[j] = bi[HH + colBase + j];
    biN[j] = bi[2 * HH + colBase + j];
    bhc[j] = bhn[colBase + j];
  }

  const float* xbase = data + (size_t)(bg * 16 + l15) * TT * FF;
  float hp[4] = {0.f, 0.f, 0.f, 0.f};  // fp32 carry: batch l15, cols colBase+j

  for (int t = 0; t < TT; ++t) {
    // ---- xg phase (h-independent; issues before the poll, hides under it) --
    f32x4 accR = {0.f, 0.f, 0.f, 0.f};
    f32x4 accZ = {0.f, 0.f, 0.f, 0.f};
    f32x4 xN   = {0.f, 0.f, 0.f, 0.f};
    {
      const float* xr = xbase + (size_t)t * FF;
#pragma unroll
      for (int ks = 0; ks < 8; ++ks) {
        float4 x0 = *(const float4*)(xr + ks * 32 + lg * 8);
        float4 x1 = *(const float4*)(xr + ks * 32 + lg * 8 + 4);
        union { short8 s; unsigned u[4]; } a;
        a.u[0] = pk2(x0.x, x0.y); a.u[1] = pk2(x0.z, x0.w);
        a.u[2] = pk2(x1.x, x1.y); a.u[3] = pk2(x1.z, x1.w);
        accR = MFMA(wif[0][ks], a.s, accR);
        accZ = MFMA(wif[1][ks], a.s, accZ);
        xN   = MFMA(wif[2][ks], a.s, xN);
      }
    }

    // ---- tagged poll: reload own fragments until all 32 chunk-tags == t ----
    const u32 tag = (u32)t;
    const u32* hb = hbuf + ((size_t)(unit * 2 + (t & 1)) << 13);  // 16*512 u32
    U4 q[32];
    while (true) {
#pragma unroll
      for (int ks = 0; ks < 16; ++ks) {
        const u32* p = hb + l15 * 512 + ks * 32 + lg * 8;
        asm volatile("global_load_dwordx4 %0, %1, off sc0 sc1"
                     : "=v"(q[2 * ks].v) : "v"(p));
        asm volatile("global_load_dwordx4 %0, %1, off sc0 sc1"
                     : "=v"(q[2 * ks + 1].v) : "v"(p + 4));
      }
      asm volatile("s_waitcnt vmcnt(0)" ::: "memory");
      u32 bad = 0;
#pragma unroll
      for (int c = 0; c < 32; ++c) {
        bad |= (q[c].u[0] ^ tag) & 0xffffu;   // tag of 8B granule {w0,w1}
        bad |= (q[c].u[3] ^ tag) & 0xffffu;   // tag of 8B granule {w2,w3}
      }
      if (__all(bad == 0)) break;
    }

    // ---- pack B-fragments (strip tags) + hg MFMAs ----
    f32x4 hN = {0.f, 0.f, 0.f, 0.f};
#pragma unroll
    for (int ks = 0; ks < 16; ++ks) {
      union { short8 s; unsigned u[4]; } a;
#pragma unroll
      for (int i = 0; i < 2; ++i) {
        const U4& c = q[2 * ks + i];
        a.u[2 * i]     = __builtin_amdgcn_perm(c.u[1], c.u[0], 0x07060302u);
        a.u[2 * i + 1] = __builtin_amdgcn_perm(c.u[3], c.u[2], 0x07060302u);
      }
      accR = MFMA(whf[0][ks], a.s, accR);
      accZ = MFMA(whf[1][ks], a.s, accZ);
      hN   = MFMA(whf[2][ks], a.s, hN);
    }

    // ---- gates: lane holds (batch=l15, cols=colBase..+3) ----
    float hv[4];
#pragma unroll
    for (int j = 0; j < 4; ++j) {
      float r = sigm(accR[j] + biR[j]);
      float z = sigm(accZ[j] + biZ[j]);
      float e = __expf(2.f * (xN[j] + biN[j] + r * (hN[j] + bhc[j])));
      float n = 1.f - 2.f * __builtin_amdgcn_rcpf(e + 1.f);  // tanh
      hv[j] = (1.f - z) * n + z * hp[j];
      hp[j] = hv[j];
    }

    // ---- publish: two tagged 8B ATOMIC SWAPS (execute at the LLC) ----
    {
      U4 w;
      const u32 wtag = (u32)(t + 1);
#pragma unroll
      for (int j = 0; j < 4; ++j)
        w.u[j] = ((u32)f2bf(hv[j]) << 16) | wtag;
      u32* ho = hbuf + ((size_t)(unit * 2 + ((t + 1) & 1)) << 13);
      u64* pdst = (u64*)(ho + l15 * 512 + s * 16 + lg * 4);
      (void)__hip_atomic_exchange(&pdst[0], w.q[0],
                                  __ATOMIC_RELAXED, __HIP_MEMORY_SCOPE_AGENT);
      (void)__hip_atomic_exchange(&pdst[1], w.q[1],
                                  __ATOMIC_RELAXED, __HIP_MEMORY_SCOPE_AGENT);
    }

    // ---- out store (off critical path): one float4 per lane ----
    *(float4*)(out + ((size_t)(bg * 16 + l15) * TT + t) * 1024 + (size_t)dir * HH + colBase)
        = make_float4(hv[0], hv[1], hv[2], hv[3]);
  }
}

extern "C" void kernel_launch(void* const* d_in, const int* in_sizes, int n_in,
                              void* d_out, int out_size, void* d_ws, size_t ws_size,
                              hipStream_t stream) {
  const float* data  = (const float*)d_in[0];
  const float* Wi_f  = (const float*)d_in[1];
  const float* bi_f  = (const float*)d_in[2];
  const float* Wh_f  = (const float*)d_in[3];
  const float* bhn_f = (const float*)d_in[4];
  const float* Wi_b  = (const float*)d_in[5];
  const float* bi_b  = (const float*)d_in[6];
  const float* Wh_b  = (const float*)d_in[7];
  const float* bhn_b = (const float*)d_in[8];
  float* out = (float*)d_out;

  // ws: [0, 512KB) tagged h double buffers (8 units x 2 x 16 x 512 u32).
  // memset(0) == valid tag-0 zero state => uniform t=0 path.
  u32* hbuf = (u32*)d_ws;
  (void)hipMemsetAsync(d_ws, 0, 524288, stream);

  gru_fused<<<NWG, NTHR, 0, stream>>>(data, Wi_f, bi_f, Wh_f, bhn_f,
                                      Wi_b, bi_b, Wh_b, bhn_b, out, hbuf);
}